// Round 1
// baseline (292.291 us; speedup 1.0000x reference)
//
#include <hip/hip_runtime.h>

#define PI_F 3.14159f
#define NQ 10

// ---------------- CSR / degree build ----------------
__global__ void k_count(const int* __restrict__ dst, int E, int* __restrict__ cnt) {
  int e = blockIdx.x * blockDim.x + threadIdx.x;
  if (e < E) atomicAdd(&cnt[dst[e]], 1);
}

__global__ __launch_bounds__(1024) void k_scan(const int* __restrict__ cnt,
                                               int* __restrict__ rowStart, int N) {
  __shared__ int buf[1024];
  __shared__ int carry;
  int t = threadIdx.x;
  if (t == 0) { carry = 0; rowStart[0] = 0; }
  __syncthreads();
  for (int c = 0; c < N; c += 1024) {
    buf[t] = cnt[c + t];
    __syncthreads();
    for (int off = 1; off < 1024; off <<= 1) {
      int x = (t >= off) ? buf[t - off] : 0;
      __syncthreads();
      buf[t] += x;
      __syncthreads();
    }
    int inc = buf[t];
    int cbase = carry;
    rowStart[c + t + 1] = cbase + inc;
    __syncthreads();
    if (t == 1023) carry = cbase + inc;
    __syncthreads();
  }
}

__global__ void k_copy_pos(const int* __restrict__ rowStart, int* __restrict__ pos, int N) {
  int i = blockIdx.x * blockDim.x + threadIdx.x;
  if (i < N) pos[i] = rowStart[i];
}

__global__ void k_fill(const int* __restrict__ dst, int E, int* __restrict__ pos,
                       int* __restrict__ eSorted) {
  int e = blockIdx.x * blockDim.x + threadIdx.x;
  if (e < E) { int s = atomicAdd(&pos[dst[e]], 1); eSorted[s] = e; }
}

__global__ void k_deg(const int* __restrict__ cnt, float* __restrict__ dinv,
                      float* __restrict__ invdeg, int N) {
  int i = blockIdx.x * blockDim.x + threadIdx.x;
  if (i < N) {
    float d = (float)cnt[i] + 1.0f;
    dinv[i] = 1.0f / sqrtf(d);
    invdeg[i] = 1.0f / d;
  }
}

__global__ void k_batch_starts(const int* __restrict__ batch, int N, int Bn,
                               int* __restrict__ starts) {
  int i = blockIdx.x * blockDim.x + threadIdx.x;
  if (i >= N) return;
  int b = batch[i];
  int bp = (i == 0) ? -1 : batch[i - 1];
  for (int g = bp + 1; g <= b; g++) starts[g] = i;
  if (i == N - 1) {
    for (int g = b + 1; g <= Bn; g++) starts[g] = N;
  }
}

__global__ void k_pool_edges(const int* __restrict__ srcA, const int* __restrict__ batch,
                             const float* __restrict__ eattr, int E,
                             float* __restrict__ psum, float* __restrict__ ecnt) {
  int e = blockIdx.x * blockDim.x + threadIdx.x;
  if (e >= E) return;
  int g = batch[srcA[e]];
  float4 v = *(const float4*)(eattr + (size_t)e * 4);
  atomicAdd(&psum[g * 4 + 0], v.x);
  atomicAdd(&psum[g * 4 + 1], v.y);
  atomicAdd(&psum[g * 4 + 2], v.z);
  atomicAdd(&psum[g * 4 + 3], v.w);
  atomicAdd(&ecnt[g], 1.0f);
}

// ---------------- fp32 tiled GEMM: C = A(MxK) * B(KxN) ----------------
__global__ __launch_bounds__(256) void k_gemm(const float* __restrict__ A,
                                              const float* __restrict__ B,
                                              float* __restrict__ C,
                                              int M, int K, int N) {
  __shared__ float As[64][36];  // padded: 36*4=144B (16B multiple)
  __shared__ float Bs[32][68];  // padded: 68*4=272B (16B multiple)
  int t = threadIdx.x;
  int tx = t & 15, ty = t >> 4;
  int row0 = blockIdx.y * 64, col0 = blockIdx.x * 64;
  float acc[4][4] = {};
  for (int k0 = 0; k0 < K; k0 += 32) {
#pragma unroll
    for (int rep = 0; rep < 2; rep++) {
      int slot = t + rep * 256;
      int r = slot >> 3;
      int cg = (slot & 7) << 2;
      float4 v = *(const float4*)(A + (size_t)(row0 + r) * K + (k0 + cg));
      *(float4*)&As[r][cg] = v;
      int r2 = slot >> 4;
      int cg2 = (slot & 15) << 2;
      float4 w = *(const float4*)(B + (size_t)(k0 + r2) * N + (col0 + cg2));
      *(float4*)&Bs[r2][cg2] = w;
    }
    __syncthreads();
#pragma unroll
    for (int kk = 0; kk < 32; kk++) {
      float av[4];
      av[0] = As[ty * 4 + 0][kk];
      av[1] = As[ty * 4 + 1][kk];
      av[2] = As[ty * 4 + 2][kk];
      av[3] = As[ty * 4 + 3][kk];
      float4 b4 = *(const float4*)&Bs[kk][tx << 2];
      float bv[4] = {b4.x, b4.y, b4.z, b4.w};
#pragma unroll
      for (int i = 0; i < 4; i++)
#pragma unroll
        for (int j = 0; j < 4; j++) acc[i][j] = fmaf(av[i], bv[j], acc[i][j]);
    }
    __syncthreads();
  }
#pragma unroll
  for (int i = 0; i < 4; i++) {
    float4 v = {acc[i][0], acc[i][1], acc[i][2], acc[i][3]};
    *(float4*)(C + (size_t)(row0 + ty * 4 + i) * N + (col0 + (tx << 2))) = v;
  }
}

// ---------------- GCN aggregate + self + bias + relu ----------------
// one (node, 4-col) pair per thread; tpn = C/4 threads per node
__global__ __launch_bounds__(256) void k_gcn_combine(
    const float* __restrict__ hlin, const int* __restrict__ srcA,
    const int* __restrict__ rowStart, const int* __restrict__ eSorted,
    const float* __restrict__ dinv, const float* __restrict__ invdeg,
    const float* __restrict__ bias, float* __restrict__ hout, int N, int C, int shift) {
  int gid = blockIdx.x * blockDim.x + threadIdx.x;
  int n = gid >> shift;
  if (n >= N) return;
  int cq = (gid & ((1 << shift) - 1)) << 2;
  int e0 = rowStart[n], e1 = rowStart[n + 1];
  float di = dinv[n];
  float ax = 0.f, ay = 0.f, az = 0.f, aw = 0.f;
  for (int e = e0; e < e1; e++) {
    int eidx = eSorted[e];
    int s = srcA[eidx];
    float coef = dinv[s] * di;
    float4 v = *(const float4*)(hlin + (size_t)s * C + cq);
    ax = fmaf(coef, v.x, ax);
    ay = fmaf(coef, v.y, ay);
    az = fmaf(coef, v.z, az);
    aw = fmaf(coef, v.w, aw);
  }
  float idg = invdeg[n];
  float4 hv = *(const float4*)(hlin + (size_t)n * C + cq);
  float4 bv = *(const float4*)(bias + cq);
  float4 r;
  r.x = fmaxf(fmaf(hv.x, idg, ax) + bv.x, 0.f);
  r.y = fmaxf(fmaf(hv.y, idg, ay) + bv.y, 0.f);
  r.z = fmaxf(fmaf(hv.z, idg, az) + bv.z, 0.f);
  r.w = fmaxf(fmaf(hv.w, idg, aw) + bv.w, 0.f);
  *(float4*)(hout + (size_t)n * C + cq) = r;
}

// ---------------- fused: segment-mean -> q_in/ep -> VQC -> head ----------------
__device__ __forceinline__ void apply_ry(float* st, int w, float c, float s, int t) {
  int str = 1 << (9 - w);
#pragma unroll
  for (int r = 0; r < 2; r++) {
    int p = t + 256 * r;  // 0..511
    int lo = p & (str - 1);
    int hi = p >> (9 - w);
    int a0 = (hi << (10 - w)) + lo;
    int a1 = a0 + str;
    float x0 = st[a0], x1 = st[a1];
    st[a0] = c * x0 - s * x1;
    st[a1] = s * x0 + c * x1;
  }
}

__device__ __forceinline__ void apply_cry(float* st, int w, float c, float s, int t) {
  int ts = 1 << (8 - w);
  int lo = t & (ts - 1);
  int hi = t >> (8 - w);
  int a0 = (hi << (10 - w)) + (ts << 1) + lo;  // control bit set
  int a1 = a0 + ts;
  float x0 = st[a0], x1 = st[a1];
  st[a0] = c * x0 - s * x1;
  st[a1] = s * x0 + c * x1;
}

__global__ __launch_bounds__(256) void k_vqc_head(
    const float* __restrict__ h2, const int* __restrict__ starts,
    const float* __restrict__ psum, const float* __restrict__ ecnt,
    const float* __restrict__ projW, const float* __restrict__ projb,
    const float* __restrict__ vqcW, const float* __restrict__ epW,
    const float* __restrict__ epb, const float* __restrict__ cW1,
    const float* __restrict__ cb1, const float* __restrict__ cW2,
    const float* __restrict__ cb2, float* __restrict__ out) {
  int g = blockIdx.x;
  int t = threadIdx.x;
  __shared__ float st[1024];
  __shared__ float emb[128];
  __shared__ float csc[59], css[59];  // 0..9 q_in, 10..49 weights, 50..58 ep
  __shared__ float zred[4][NQ];
  __shared__ float zq[NQ];
  __shared__ float hid[16];

  int s0 = starts[g], s1 = starts[g + 1];
  int cntn = s1 - s0;
  float invc = 1.0f / (float)(cntn > 0 ? cntn : 1);
  if (t < 128) {
    float sum = 0.f;
    for (int i = s0; i < s1; i++) sum += h2[(size_t)i * 128 + t];
    emb[t] = sum * invc;
  }
  // zero the state while emb threads work
  st[t] = 0.f; st[t + 256] = 0.f; st[t + 512] = 0.f; st[t + 768] = 0.f;
  __syncthreads();

  if (t < NQ) {
    float sum = projb[t];
    for (int k = 0; k < 128; k++) sum = fmaf(emb[k], projW[k * NQ + t], sum);
    float th = tanhf(sum) * PI_F * 0.5f;
    csc[t] = cosf(th);
    css[t] = sinf(th);
  } else if (t < NQ + 40) {
    float th = vqcW[t - NQ] * 0.5f;
    csc[t] = cosf(th);
    css[t] = sinf(th);
  } else if (t < 59) {
    int i = t - 50;
    float icnt = 1.0f / fmaxf(ecnt[g], 1.0f);
    float sum = epb[i];
    for (int j = 0; j < 4; j++) sum = fmaf(psum[g * 4 + j] * icnt, epW[j * 9 + i], sum);
    float th = sum * 0.5f;
    csc[t] = cosf(th);
    css[t] = sinf(th);
  }
  if (t == 0) st[0] = 1.0f;
  __syncthreads();

  // initial RY layer (q_in angles)
  for (int i = 0; i < NQ; i++) {
    apply_ry(st, i, csc[i], css[i], t);
    __syncthreads();
  }
  // entangling layers
  for (int L = 0; L < 4; L++) {
    for (int i = 0; i < NQ; i++) {
      apply_ry(st, i, csc[10 + L * 10 + i], css[10 + L * 10 + i], t);
      __syncthreads();
    }
    for (int i = 0; i < NQ - 1; i++) {
      apply_cry(st, i, csc[50 + i], css[50 + i], t);
      __syncthreads();
    }
  }

  // Z expectations
  float z[NQ];
#pragma unroll
  for (int i = 0; i < NQ; i++) z[i] = 0.f;
#pragma unroll
  for (int r = 0; r < 4; r++) {
    int a = t + 256 * r;
    float p = st[a] * st[a];
#pragma unroll
    for (int i = 0; i < NQ; i++) z[i] += ((a >> (9 - i)) & 1) ? -p : p;
  }
#pragma unroll
  for (int off = 32; off >= 1; off >>= 1) {
#pragma unroll
    for (int i = 0; i < NQ; i++) z[i] += __shfl_down(z[i], off, 64);
  }
  int wave = t >> 6, lane = t & 63;
  if (lane == 0) {
#pragma unroll
    for (int i = 0; i < NQ; i++) zred[wave][i] = z[i];
  }
  __syncthreads();
  if (t < NQ) zq[t] = zred[0][t] + zred[1][t] + zred[2][t] + zred[3][t];
  __syncthreads();

  // head: hid = relu([emb, zq] @ cW1 + cb1); out = hid @ cW2 + cb2
  if (t < 16) {
    float sum = cb1[t];
    for (int k = 0; k < 128; k++) sum = fmaf(emb[k], cW1[k * 16 + t], sum);
    for (int k = 0; k < NQ; k++) sum = fmaf(zq[k], cW1[(128 + k) * 16 + t], sum);
    hid[t] = fmaxf(sum, 0.f);
  }
  __syncthreads();
  if (t == 0) {
    float sum = cb2[0];
    for (int j = 0; j < 16; j++) sum = fmaf(hid[j], cW2[j], sum);
    out[g] = sum;
  }
}

extern "C" void kernel_launch(void* const* d_in, const int* in_sizes, int n_in,
                              void* d_out, int out_size, void* d_ws, size_t ws_size,
                              hipStream_t stream) {
  const float* x = (const float*)d_in[0];
  const int* ei = (const int*)d_in[1];
  const int* batch = (const int*)d_in[2];
  const float* eattr = (const float*)d_in[3];
  const float* W1 = (const float*)d_in[4];
  const float* b1 = (const float*)d_in[5];
  const float* W2 = (const float*)d_in[6];
  const float* b2 = (const float*)d_in[7];
  const float* projW = (const float*)d_in[8];
  const float* projb = (const float*)d_in[9];
  const float* vqcW = (const float*)d_in[10];
  const float* epW = (const float*)d_in[11];
  const float* epb = (const float*)d_in[12];
  const float* cW1 = (const float*)d_in[13];
  const float* cb1 = (const float*)d_in[14];
  const float* cW2 = (const float*)d_in[15];
  const float* cb2 = (const float*)d_in[16];
  float* out = (float*)d_out;

  const int N = in_sizes[0] / 128;  // 32768
  const int E = in_sizes[1] / 2;    // 131072
  const int Bn = out_size;          // 1024

  const int* srcA = ei;
  const int* dstA = ei + E;

  char* ws = (char*)d_ws;
  float* bufA = (float*)ws;                                // 32 MB: h1lin, then h2lin
  float* bufB = (float*)(ws + ((size_t)32 << 20));         // 32 MB: h1, then h2
  size_t off = (size_t)64 << 20;
  auto alloc = [&](size_t bytes) {
    size_t o = off;
    off += (bytes + 255) & ~(size_t)255;
    return o;
  };
  int* cnt = (int*)(ws + alloc((size_t)N * 4));
  float* psum = (float*)(ws + alloc((size_t)Bn * 4 * 4));
  float* ecnt = (float*)(ws + alloc((size_t)Bn * 4));
  size_t zeroEnd = off;
  int* rowStart = (int*)(ws + alloc((size_t)(N + 1) * 4));
  int* pos = (int*)(ws + alloc((size_t)N * 4));
  int* eSorted = (int*)(ws + alloc((size_t)E * 4));
  float* dinv = (float*)(ws + alloc((size_t)N * 4));
  float* invdeg = (float*)(ws + alloc((size_t)N * 4));
  int* starts = (int*)(ws + alloc((size_t)(Bn + 1) * 4));

  // zero the accumulators (cnt, psum, ecnt are contiguous from 64MB)
  hipMemsetAsync(ws + ((size_t)64 << 20), 0, zeroEnd - ((size_t)64 << 20), stream);

  int eblocks = (E + 255) / 256;
  int nblocks = (N + 255) / 256;

  k_count<<<eblocks, 256, 0, stream>>>(dstA, E, cnt);
  k_scan<<<1, 1024, 0, stream>>>(cnt, rowStart, N);
  k_copy_pos<<<nblocks, 256, 0, stream>>>(rowStart, pos, N);
  k_fill<<<eblocks, 256, 0, stream>>>(dstA, E, pos, eSorted);
  k_deg<<<nblocks, 256, 0, stream>>>(cnt, dinv, invdeg, N);
  k_batch_starts<<<nblocks, 256, 0, stream>>>(batch, N, Bn, starts);
  k_pool_edges<<<eblocks, 256, 0, stream>>>(srcA, batch, eattr, E, psum, ecnt);

  // conv1: h1lin = x @ W1 (N x 256)
  {
    dim3 grid(256 / 64, N / 64);
    k_gemm<<<grid, 256, 0, stream>>>(x, W1, bufA, N, 128, 256);
  }
  // combine1 -> h1 (N x 256), 64 threads per node
  k_gcn_combine<<<(N * 64) / 256, 256, 0, stream>>>(bufA, srcA, rowStart, eSorted, dinv,
                                                    invdeg, b1, bufB, N, 256, 6);
  // conv2: h2lin = h1 @ W2 (N x 128)
  {
    dim3 grid(128 / 64, N / 64);
    k_gemm<<<grid, 256, 0, stream>>>(bufB, W2, bufA, N, 256, 128);
  }
  // combine2 -> h2 (N x 128), 32 threads per node
  k_gcn_combine<<<(N * 32) / 256, 256, 0, stream>>>(bufA, srcA, rowStart, eSorted, dinv,
                                                    invdeg, b2, bufB, N, 128, 5);
  // fused tail: segment-mean + q_in/ep + VQC + head
  k_vqc_head<<<Bn, 256, 0, stream>>>(bufB, starts, psum, ecnt, projW, projb, vqcW, epW,
                                     epb, cW1, cb1, cW2, cb2, out);
}

// Round 2
// 236.181 us; speedup vs baseline: 1.2376x; 1.2376x over previous
//
#include <hip/hip_runtime.h>

#define PI_F 3.14159f
#define NQ 10

// ---------------- edge pass: degree count + edge-attr pooling ----------------
__global__ void k_edge_setup(const int* __restrict__ dstA, const int* __restrict__ srcA,
                             const int* __restrict__ batch, const float* __restrict__ eattr,
                             int E, int* __restrict__ cnt, float* __restrict__ psum,
                             float* __restrict__ ecnt) {
  int e = blockIdx.x * blockDim.x + threadIdx.x;
  if (e >= E) return;
  atomicAdd(&cnt[dstA[e]], 1);
  int g = batch[srcA[e]];
  float4 v = *(const float4*)(eattr + (size_t)e * 4);
  atomicAdd(&psum[g * 4 + 0], v.x);
  atomicAdd(&psum[g * 4 + 1], v.y);
  atomicAdd(&psum[g * 4 + 2], v.z);
  atomicAdd(&psum[g * 4 + 3], v.w);
  atomicAdd(&ecnt[g], 1.0f);
}

// ---------------- two-level scan ----------------
// level 1: per-block (1024) inclusive scan in LDS, emit block sums
__global__ __launch_bounds__(1024) void k_scan1(const int* __restrict__ cnt,
                                                int* __restrict__ incl,
                                                int* __restrict__ bsum) {
  __shared__ int buf[1024];
  int t = threadIdx.x;
  int base = blockIdx.x << 10;
  buf[t] = cnt[base + t];
  __syncthreads();
#pragma unroll
  for (int off = 1; off < 1024; off <<= 1) {
    int x = (t >= off) ? buf[t - off] : 0;
    __syncthreads();
    buf[t] += x;
    __syncthreads();
  }
  incl[base + t] = buf[t];
  if (t == 1023) bsum[blockIdx.x] = buf[t];
}

// level 2: exclusive scan of the (<=64) block sums, one wave
__global__ void k_scan2(int* __restrict__ bsum, int nb) {
  int t = threadIdx.x;  // 64 threads
  int v = (t < nb) ? bsum[t] : 0;
  int orig = v;
#pragma unroll
  for (int off = 1; off < 64; off <<= 1) {
    int x = __shfl_up(v, off, 64);
    if (t >= off) v += x;
  }
  if (t < nb) bsum[t] = v - orig;  // exclusive prefix
}

// level 3 + node setup: rowStart, pos, deg terms, batch starts
__global__ void k_node_setup(const int* __restrict__ cnt, const int* __restrict__ incl,
                             const int* __restrict__ bsum, const int* __restrict__ batch,
                             int N, int Bn, int* __restrict__ rowStart,
                             int* __restrict__ pos, float* __restrict__ dinv,
                             float* __restrict__ invdeg, int* __restrict__ starts) {
  int i = blockIdx.x * blockDim.x + threadIdx.x;
  if (i >= N) return;
  int c = cnt[i];
  int inc = incl[i] + bsum[i >> 10];
  rowStart[i + 1] = inc;
  pos[i] = inc - c;
  if (i == 0) rowStart[0] = 0;
  float d = (float)c + 1.0f;
  dinv[i] = 1.0f / sqrtf(d);
  invdeg[i] = 1.0f / d;
  int b = batch[i];
  int bp = (i == 0) ? -1 : batch[i - 1];
  for (int g = bp + 1; g <= b; g++) starts[g] = i;
  if (i == N - 1) {
    for (int g = b + 1; g <= Bn; g++) starts[g] = N;
  }
}

__global__ void k_fill(const int* __restrict__ dst, int E, int* __restrict__ pos,
                       int* __restrict__ eSorted) {
  int e = blockIdx.x * blockDim.x + threadIdx.x;
  if (e < E) { int s = atomicAdd(&pos[dst[e]], 1); eSorted[s] = e; }
}

// ---------------- fp32 tiled GEMM: C = A(MxK) * B(KxN) ----------------
__global__ __launch_bounds__(256) void k_gemm(const float* __restrict__ A,
                                              const float* __restrict__ B,
                                              float* __restrict__ C,
                                              int M, int K, int N) {
  __shared__ float As[64][36];
  __shared__ float Bs[32][68];
  int t = threadIdx.x;
  int tx = t & 15, ty = t >> 4;
  int row0 = blockIdx.y * 64, col0 = blockIdx.x * 64;
  float acc[4][4] = {};
  for (int k0 = 0; k0 < K; k0 += 32) {
#pragma unroll
    for (int rep = 0; rep < 2; rep++) {
      int slot = t + rep * 256;
      int r = slot >> 3;
      int cg = (slot & 7) << 2;
      float4 v = *(const float4*)(A + (size_t)(row0 + r) * K + (k0 + cg));
      *(float4*)&As[r][cg] = v;
      int r2 = slot >> 4;
      int cg2 = (slot & 15) << 2;
      float4 w = *(const float4*)(B + (size_t)(k0 + r2) * N + (col0 + cg2));
      *(float4*)&Bs[r2][cg2] = w;
    }
    __syncthreads();
#pragma unroll
    for (int kk = 0; kk < 32; kk++) {
      float av[4];
      av[0] = As[ty * 4 + 0][kk];
      av[1] = As[ty * 4 + 1][kk];
      av[2] = As[ty * 4 + 2][kk];
      av[3] = As[ty * 4 + 3][kk];
      float4 b4 = *(const float4*)&Bs[kk][tx << 2];
      float bv[4] = {b4.x, b4.y, b4.z, b4.w};
#pragma unroll
      for (int i = 0; i < 4; i++)
#pragma unroll
        for (int j = 0; j < 4; j++) acc[i][j] = fmaf(av[i], bv[j], acc[i][j]);
    }
    __syncthreads();
  }
#pragma unroll
  for (int i = 0; i < 4; i++) {
    float4 v = {acc[i][0], acc[i][1], acc[i][2], acc[i][3]};
    *(float4*)(C + (size_t)(row0 + ty * 4 + i) * N + (col0 + (tx << 2))) = v;
  }
}

// ---------------- GCN aggregate + self + bias + relu ----------------
__global__ __launch_bounds__(256) void k_gcn_combine(
    const float* __restrict__ hlin, const int* __restrict__ srcA,
    const int* __restrict__ rowStart, const int* __restrict__ eSorted,
    const float* __restrict__ dinv, const float* __restrict__ invdeg,
    const float* __restrict__ bias, float* __restrict__ hout, int N, int C, int shift) {
  int gid = blockIdx.x * blockDim.x + threadIdx.x;
  int n = gid >> shift;
  if (n >= N) return;
  int cq = (gid & ((1 << shift) - 1)) << 2;
  int e0 = rowStart[n], e1 = rowStart[n + 1];
  float di = dinv[n];
  float ax = 0.f, ay = 0.f, az = 0.f, aw = 0.f;
  for (int e = e0; e < e1; e++) {
    int eidx = eSorted[e];
    int s = srcA[eidx];
    float coef = dinv[s] * di;
    float4 v = *(const float4*)(hlin + (size_t)s * C + cq);
    ax = fmaf(coef, v.x, ax);
    ay = fmaf(coef, v.y, ay);
    az = fmaf(coef, v.z, az);
    aw = fmaf(coef, v.w, aw);
  }
  float idg = invdeg[n];
  float4 hv = *(const float4*)(hlin + (size_t)n * C + cq);
  float4 bv = *(const float4*)(bias + cq);
  float4 r;
  r.x = fmaxf(fmaf(hv.x, idg, ax) + bv.x, 0.f);
  r.y = fmaxf(fmaf(hv.y, idg, ay) + bv.y, 0.f);
  r.z = fmaxf(fmaf(hv.z, idg, az) + bv.z, 0.f);
  r.w = fmaxf(fmaf(hv.w, idg, aw) + bv.w, 0.f);
  *(float4*)(hout + (size_t)n * C + cq) = r;
}

// ---------------- fused: segment-mean -> q_in/ep -> VQC -> head ----------------
__device__ __forceinline__ void apply_ry(float* st, int w, float c, float s, int t) {
  int str = 1 << (9 - w);
#pragma unroll
  for (int r = 0; r < 2; r++) {
    int p = t + 256 * r;
    int lo = p & (str - 1);
    int hi = p >> (9 - w);
    int a0 = (hi << (10 - w)) + lo;
    int a1 = a0 + str;
    float x0 = st[a0], x1 = st[a1];
    st[a0] = c * x0 - s * x1;
    st[a1] = s * x0 + c * x1;
  }
}

__device__ __forceinline__ void apply_cry(float* st, int w, float c, float s, int t) {
  int ts = 1 << (8 - w);
  int lo = t & (ts - 1);
  int hi = t >> (8 - w);
  int a0 = (hi << (10 - w)) + (ts << 1) + lo;
  int a1 = a0 + ts;
  float x0 = st[a0], x1 = st[a1];
  st[a0] = c * x0 - s * x1;
  st[a1] = s * x0 + c * x1;
}

__global__ __launch_bounds__(256) void k_vqc_head(
    const float* __restrict__ h2, const int* __restrict__ starts,
    const float* __restrict__ psum, const float* __restrict__ ecnt,
    const float* __restrict__ projW, const float* __restrict__ projb,
    const float* __restrict__ vqcW, const float* __restrict__ epW,
    const float* __restrict__ epb, const float* __restrict__ cW1,
    const float* __restrict__ cb1, const float* __restrict__ cW2,
    const float* __restrict__ cb2, float* __restrict__ out) {
  int g = blockIdx.x;
  int t = threadIdx.x;
  __shared__ float st[1024];
  __shared__ float emb[128];
  __shared__ float csc[59], css[59];
  __shared__ float zred[4][NQ];
  __shared__ float zq[NQ];
  __shared__ float hid[16];

  int s0 = starts[g], s1 = starts[g + 1];
  int cntn = s1 - s0;
  float invc = 1.0f / (float)(cntn > 0 ? cntn : 1);
  if (t < 128) {
    float sum = 0.f;
    for (int i = s0; i < s1; i++) sum += h2[(size_t)i * 128 + t];
    emb[t] = sum * invc;
  }
  st[t] = 0.f; st[t + 256] = 0.f; st[t + 512] = 0.f; st[t + 768] = 0.f;
  __syncthreads();

  if (t < NQ) {
    float sum = projb[t];
    for (int k = 0; k < 128; k++) sum = fmaf(emb[k], projW[k * NQ + t], sum);
    float th = tanhf(sum) * PI_F * 0.5f;
    csc[t] = cosf(th);
    css[t] = sinf(th);
  } else if (t < NQ + 40) {
    float th = vqcW[t - NQ] * 0.5f;
    csc[t] = cosf(th);
    css[t] = sinf(th);
  } else if (t < 59) {
    int i = t - 50;
    float icnt = 1.0f / fmaxf(ecnt[g], 1.0f);
    float sum = epb[i];
    for (int j = 0; j < 4; j++) sum = fmaf(psum[g * 4 + j] * icnt, epW[j * 9 + i], sum);
    float th = sum * 0.5f;
    csc[t] = cosf(th);
    css[t] = sinf(th);
  }
  if (t == 0) st[0] = 1.0f;
  __syncthreads();

  for (int i = 0; i < NQ; i++) {
    apply_ry(st, i, csc[i], css[i], t);
    __syncthreads();
  }
  for (int L = 0; L < 4; L++) {
    for (int i = 0; i < NQ; i++) {
      apply_ry(st, i, csc[10 + L * 10 + i], css[10 + L * 10 + i], t);
      __syncthreads();
    }
    for (int i = 0; i < NQ - 1; i++) {
      apply_cry(st, i, csc[50 + i], css[50 + i], t);
      __syncthreads();
    }
  }

  float z[NQ];
#pragma unroll
  for (int i = 0; i < NQ; i++) z[i] = 0.f;
#pragma unroll
  for (int r = 0; r < 4; r++) {
    int a = t + 256 * r;
    float p = st[a] * st[a];
#pragma unroll
    for (int i = 0; i < NQ; i++) z[i] += ((a >> (9 - i)) & 1) ? -p : p;
  }
#pragma unroll
  for (int off = 32; off >= 1; off >>= 1) {
#pragma unroll
    for (int i = 0; i < NQ; i++) z[i] += __shfl_down(z[i], off, 64);
  }
  int wave = t >> 6, lane = t & 63;
  if (lane == 0) {
#pragma unroll
    for (int i = 0; i < NQ; i++) zred[wave][i] = z[i];
  }
  __syncthreads();
  if (t < NQ) zq[t] = zred[0][t] + zred[1][t] + zred[2][t] + zred[3][t];
  __syncthreads();

  if (t < 16) {
    float sum = cb1[t];
    for (int k = 0; k < 128; k++) sum = fmaf(emb[k], cW1[k * 16 + t], sum);
    for (int k = 0; k < NQ; k++) sum = fmaf(zq[k], cW1[(128 + k) * 16 + t], sum);
    hid[t] = fmaxf(sum, 0.f);
  }
  __syncthreads();
  if (t == 0) {
    float sum = cb2[0];
    for (int j = 0; j < 16; j++) sum = fmaf(hid[j], cW2[j], sum);
    out[g] = sum;
  }
}

extern "C" void kernel_launch(void* const* d_in, const int* in_sizes, int n_in,
                              void* d_out, int out_size, void* d_ws, size_t ws_size,
                              hipStream_t stream) {
  const float* x = (const float*)d_in[0];
  const int* ei = (const int*)d_in[1];
  const int* batch = (const int*)d_in[2];
  const float* eattr = (const float*)d_in[3];
  const float* W1 = (const float*)d_in[4];
  const float* b1 = (const float*)d_in[5];
  const float* W2 = (const float*)d_in[6];
  const float* b2 = (const float*)d_in[7];
  const float* projW = (const float*)d_in[8];
  const float* projb = (const float*)d_in[9];
  const float* vqcW = (const float*)d_in[10];
  const float* epW = (const float*)d_in[11];
  const float* epb = (const float*)d_in[12];
  const float* cW1 = (const float*)d_in[13];
  const float* cb1 = (const float*)d_in[14];
  const float* cW2 = (const float*)d_in[15];
  const float* cb2 = (const float*)d_in[16];
  float* out = (float*)d_out;

  const int N = in_sizes[0] / 128;  // 32768
  const int E = in_sizes[1] / 2;    // 131072
  const int Bn = out_size;          // 1024

  const int* srcA = ei;
  const int* dstA = ei + E;

  char* ws = (char*)d_ws;
  float* bufA = (float*)ws;                         // 32 MB
  float* bufB = (float*)(ws + ((size_t)32 << 20));  // 32 MB
  size_t off = (size_t)64 << 20;
  auto alloc = [&](size_t bytes) {
    size_t o = off;
    off += (bytes + 255) & ~(size_t)255;
    return o;
  };
  int* cnt = (int*)(ws + alloc((size_t)N * 4));
  float* psum = (float*)(ws + alloc((size_t)Bn * 4 * 4));
  float* ecnt = (float*)(ws + alloc((size_t)Bn * 4));
  size_t zeroEnd = off;
  int* rowStart = (int*)(ws + alloc((size_t)(N + 1) * 4));
  int* pos = (int*)(ws + alloc((size_t)N * 4));
  int* eSorted = (int*)(ws + alloc((size_t)E * 4));
  float* dinv = (float*)(ws + alloc((size_t)N * 4));
  float* invdeg = (float*)(ws + alloc((size_t)N * 4));
  int* starts = (int*)(ws + alloc((size_t)(Bn + 1) * 4));
  int* incl = (int*)(ws + alloc((size_t)N * 4));
  int* bsum = (int*)(ws + alloc(64 * 4));

  hipMemsetAsync(ws + ((size_t)64 << 20), 0, zeroEnd - ((size_t)64 << 20), stream);

  int eblocks = (E + 255) / 256;
  int nblocks = (N + 255) / 256;
  int nb1024 = N >> 10;  // 32

  k_edge_setup<<<eblocks, 256, 0, stream>>>(dstA, srcA, batch, eattr, E, cnt, psum, ecnt);
  k_scan1<<<nb1024, 1024, 0, stream>>>(cnt, incl, bsum);
  k_scan2<<<1, 64, 0, stream>>>(bsum, nb1024);
  k_node_setup<<<nblocks, 256, 0, stream>>>(cnt, incl, bsum, batch, N, Bn, rowStart, pos,
                                            dinv, invdeg, starts);
  k_fill<<<eblocks, 256, 0, stream>>>(dstA, E, pos, eSorted);

  {
    dim3 grid(256 / 64, N / 64);
    k_gemm<<<grid, 256, 0, stream>>>(x, W1, bufA, N, 128, 256);
  }
  k_gcn_combine<<<(N * 64) / 256, 256, 0, stream>>>(bufA, srcA, rowStart, eSorted, dinv,
                                                    invdeg, b1, bufB, N, 256, 6);
  {
    dim3 grid(128 / 64, N / 64);
    k_gemm<<<grid, 256, 0, stream>>>(bufB, W2, bufA, N, 256, 128);
  }
  k_gcn_combine<<<(N * 32) / 256, 256, 0, stream>>>(bufA, srcA, rowStart, eSorted, dinv,
                                                    invdeg, b2, bufB, N, 128, 5);
  k_vqc_head<<<Bn, 256, 0, stream>>>(bufB, starts, psum, ecnt, projW, projb, vqcW, epW,
                                     epb, cW1, cb1, cW2, cb2, out);
}

// Round 3
// 209.174 us; speedup vs baseline: 1.3974x; 1.1291x over previous
//
#include <hip/hip_runtime.h>

#define PI_F 3.14159f
#define NQ 10

// ---------------- edge pass: degree count + per-src edge-attr bins ----------------
__global__ void k_edge_setup(const int* __restrict__ dstA, const int* __restrict__ srcA,
                             const float* __restrict__ eattr, int E,
                             int* __restrict__ cnt, float* __restrict__ nsum4,
                             float* __restrict__ necnt) {
  int e = blockIdx.x * blockDim.x + threadIdx.x;
  if (e >= E) return;
  atomicAdd(&cnt[dstA[e]], 1);
  int s = srcA[e];
  float4 v = *(const float4*)(eattr + (size_t)e * 4);
  atomicAdd(&nsum4[(size_t)s * 4 + 0], v.x);
  atomicAdd(&nsum4[(size_t)s * 4 + 1], v.y);
  atomicAdd(&nsum4[(size_t)s * 4 + 2], v.z);
  atomicAdd(&nsum4[(size_t)s * 4 + 3], v.w);
  atomicAdd(&necnt[s], 1.0f);
}

// ---------------- scan level 1: per-block (1024) inclusive scan ----------------
__global__ __launch_bounds__(1024) void k_scan1(const int* __restrict__ cnt,
                                                int* __restrict__ incl,
                                                int* __restrict__ bsum) {
  __shared__ int buf[1024];
  int t = threadIdx.x;
  int base = blockIdx.x << 10;
  buf[t] = cnt[base + t];
  __syncthreads();
#pragma unroll
  for (int off = 1; off < 1024; off <<= 1) {
    int x = (t >= off) ? buf[t - off] : 0;
    __syncthreads();
    buf[t] += x;
    __syncthreads();
  }
  incl[base + t] = buf[t];
  if (t == 1023) bsum[blockIdx.x] = buf[t];
}

// ---------------- node setup: rowStart, pos, deg terms, batch starts ----------------
// folds the level-2 scan (<=32 block sums) in-kernel: uniform per block.
__global__ void k_node_setup(const int* __restrict__ cnt, const int* __restrict__ incl,
                             const int* __restrict__ bsum, const int* __restrict__ batch,
                             int N, int Bn, int* __restrict__ rowStart,
                             int* __restrict__ pos, float* __restrict__ dinv,
                             float* __restrict__ invdeg, int* __restrict__ starts) {
  int i = blockIdx.x * blockDim.x + threadIdx.x;
  if (i >= N) return;
  int blk = i >> 10;  // uniform within a 256-thread block (256 | 1024)
  int pre = 0;
  for (int j = 0; j < blk; j++) pre += bsum[j];
  int c = cnt[i];
  int inc = incl[i] + pre;
  rowStart[i + 1] = inc;
  pos[i] = inc - c;
  if (i == 0) rowStart[0] = 0;
  float d = (float)c + 1.0f;
  dinv[i] = 1.0f / sqrtf(d);
  invdeg[i] = 1.0f / d;
  int b = batch[i];
  int bp = (i == 0) ? -1 : batch[i - 1];
  for (int g = bp + 1; g <= b; g++) starts[g] = i;
  if (i == N - 1) {
    for (int g = b + 1; g <= Bn; g++) starts[g] = N;
  }
}

// ---------------- fill: counting-sort edges by dst; store src + dinv[src] ----------------
__global__ void k_fill(const int* __restrict__ dst, const int* __restrict__ srcA,
                       const float* __restrict__ dinv, int E, int* __restrict__ pos,
                       int* __restrict__ srcSorted, float* __restrict__ dcoef) {
  int e = blockIdx.x * blockDim.x + threadIdx.x;
  if (e >= E) return;
  int s = srcA[e];
  int slot = atomicAdd(&pos[dst[e]], 1);
  srcSorted[slot] = s;
  dcoef[slot] = dinv[s];
}

// ---------------- fp32 tiled GEMM: C = A(MxK) * B(KxN) ----------------
__global__ __launch_bounds__(256) void k_gemm(const float* __restrict__ A,
                                              const float* __restrict__ B,
                                              float* __restrict__ C,
                                              int M, int K, int N) {
  __shared__ float As[64][36];
  __shared__ float Bs[32][68];
  int t = threadIdx.x;
  int tx = t & 15, ty = t >> 4;
  int row0 = blockIdx.y * 64, col0 = blockIdx.x * 64;
  float acc[4][4] = {};
  for (int k0 = 0; k0 < K; k0 += 32) {
#pragma unroll
    for (int rep = 0; rep < 2; rep++) {
      int slot = t + rep * 256;
      int r = slot >> 3;
      int cg = (slot & 7) << 2;
      float4 v = *(const float4*)(A + (size_t)(row0 + r) * K + (k0 + cg));
      *(float4*)&As[r][cg] = v;
      int r2 = slot >> 4;
      int cg2 = (slot & 15) << 2;
      float4 w = *(const float4*)(B + (size_t)(k0 + r2) * N + (col0 + cg2));
      *(float4*)&Bs[r2][cg2] = w;
    }
    __syncthreads();
#pragma unroll
    for (int kk = 0; kk < 32; kk++) {
      float av[4];
      av[0] = As[ty * 4 + 0][kk];
      av[1] = As[ty * 4 + 1][kk];
      av[2] = As[ty * 4 + 2][kk];
      av[3] = As[ty * 4 + 3][kk];
      float4 b4 = *(const float4*)&Bs[kk][tx << 2];
      float bv[4] = {b4.x, b4.y, b4.z, b4.w};
#pragma unroll
      for (int i = 0; i < 4; i++)
#pragma unroll
        for (int j = 0; j < 4; j++) acc[i][j] = fmaf(av[i], bv[j], acc[i][j]);
    }
    __syncthreads();
  }
#pragma unroll
  for (int i = 0; i < 4; i++) {
    float4 v = {acc[i][0], acc[i][1], acc[i][2], acc[i][3]};
    *(float4*)(C + (size_t)(row0 + ty * 4 + i) * N + (col0 + (tx << 2))) = v;
  }
}

// ---------------- GCN aggregate + self + bias + relu ----------------
__global__ __launch_bounds__(256) void k_gcn_combine(
    const float* __restrict__ hlin, const int* __restrict__ srcSorted,
    const float* __restrict__ dcoef, const int* __restrict__ rowStart,
    const float* __restrict__ dinv, const float* __restrict__ invdeg,
    const float* __restrict__ bias, float* __restrict__ hout, int N, int C, int shift) {
  int gid = blockIdx.x * blockDim.x + threadIdx.x;
  int n = gid >> shift;
  if (n >= N) return;
  int cq = (gid & ((1 << shift) - 1)) << 2;
  int e0 = rowStart[n], e1 = rowStart[n + 1];
  float di = dinv[n];
  float ax = 0.f, ay = 0.f, az = 0.f, aw = 0.f;
  for (int e = e0; e < e1; e++) {
    int s = srcSorted[e];
    float coef = dcoef[e] * di;
    float4 v = *(const float4*)(hlin + (size_t)s * C + cq);
    ax = fmaf(coef, v.x, ax);
    ay = fmaf(coef, v.y, ay);
    az = fmaf(coef, v.z, az);
    aw = fmaf(coef, v.w, aw);
  }
  float idg = invdeg[n];
  float4 hv = *(const float4*)(hlin + (size_t)n * C + cq);
  float4 bv = *(const float4*)(bias + cq);
  float4 r;
  r.x = fmaxf(fmaf(hv.x, idg, ax) + bv.x, 0.f);
  r.y = fmaxf(fmaf(hv.y, idg, ay) + bv.y, 0.f);
  r.z = fmaxf(fmaf(hv.z, idg, az) + bv.z, 0.f);
  r.w = fmaxf(fmaf(hv.w, idg, aw) + bv.w, 0.f);
  *(float4*)(hout + (size_t)n * C + cq) = r;
}

// ---------------- fused: segment-mean + edge-pool -> q_in/ep -> VQC -> head ----------------
__device__ __forceinline__ void apply_ry(float* st, int w, float c, float s, int t) {
  int str = 1 << (9 - w);
#pragma unroll
  for (int r = 0; r < 2; r++) {
    int p = t + 256 * r;
    int lo = p & (str - 1);
    int hi = p >> (9 - w);
    int a0 = (hi << (10 - w)) + lo;
    int a1 = a0 + str;
    float x0 = st[a0], x1 = st[a1];
    st[a0] = c * x0 - s * x1;
    st[a1] = s * x0 + c * x1;
  }
}

__device__ __forceinline__ void apply_cry(float* st, int w, float c, float s, int t) {
  int ts = 1 << (8 - w);
  int lo = t & (ts - 1);
  int hi = t >> (8 - w);
  int a0 = (hi << (10 - w)) + (ts << 1) + lo;
  int a1 = a0 + ts;
  float x0 = st[a0], x1 = st[a1];
  st[a0] = c * x0 - s * x1;
  st[a1] = s * x0 + c * x1;
}

__global__ __launch_bounds__(256) void k_vqc_head(
    const float* __restrict__ h2, const int* __restrict__ starts,
    const float* __restrict__ nsum4, const float* __restrict__ necnt,
    const float* __restrict__ projW, const float* __restrict__ projb,
    const float* __restrict__ vqcW, const float* __restrict__ epW,
    const float* __restrict__ epb, const float* __restrict__ cW1,
    const float* __restrict__ cb1, const float* __restrict__ cW2,
    const float* __restrict__ cb2, float* __restrict__ out) {
  int g = blockIdx.x;
  int t = threadIdx.x;
  __shared__ float st[1024];
  __shared__ float emb[128];
  __shared__ float csc[59], css[59];
  __shared__ float pool[5];
  __shared__ float zred[4][NQ];
  __shared__ float zq[NQ];
  __shared__ float hid[16];

  int s0 = starts[g], s1 = starts[g + 1];
  int cntn = s1 - s0;
  float invc = 1.0f / (float)(cntn > 0 ? cntn : 1);
  if (t < 128) {
    float sum = 0.f;
    for (int i = s0; i < s1; i++) sum += h2[(size_t)i * 128 + t];
    emb[t] = sum * invc;
  } else if (t >= 192) {
    // wave 3: reduce per-src edge bins -> per-graph pooled sums
    int lane = t - 192;
    float p0 = 0.f, p1 = 0.f, p2 = 0.f, p3 = 0.f, pc = 0.f;
    for (int i = s0 + lane; i < s1; i += 64) {
      float4 v = *(const float4*)(nsum4 + (size_t)i * 4);
      p0 += v.x; p1 += v.y; p2 += v.z; p3 += v.w;
      pc += necnt[i];
    }
#pragma unroll
    for (int off = 32; off >= 1; off >>= 1) {
      p0 += __shfl_down(p0, off, 64);
      p1 += __shfl_down(p1, off, 64);
      p2 += __shfl_down(p2, off, 64);
      p3 += __shfl_down(p3, off, 64);
      pc += __shfl_down(pc, off, 64);
    }
    if (lane == 0) { pool[0] = p0; pool[1] = p1; pool[2] = p2; pool[3] = p3; pool[4] = pc; }
  }
  st[t] = 0.f; st[t + 256] = 0.f; st[t + 512] = 0.f; st[t + 768] = 0.f;
  __syncthreads();

  if (t < NQ) {
    float sum = projb[t];
    for (int k = 0; k < 128; k++) sum = fmaf(emb[k], projW[k * NQ + t], sum);
    float th = tanhf(sum) * PI_F * 0.5f;
    csc[t] = cosf(th);
    css[t] = sinf(th);
  } else if (t < NQ + 40) {
    float th = vqcW[t - NQ] * 0.5f;
    csc[t] = cosf(th);
    css[t] = sinf(th);
  } else if (t < 59) {
    int i = t - 50;
    float icnt = 1.0f / fmaxf(pool[4], 1.0f);
    float sum = epb[i];
    for (int j = 0; j < 4; j++) sum = fmaf(pool[j] * icnt, epW[j * 9 + i], sum);
    float th = sum * 0.5f;
    csc[t] = cosf(th);
    css[t] = sinf(th);
  }
  if (t == 0) st[0] = 1.0f;
  __syncthreads();

  for (int i = 0; i < NQ; i++) {
    apply_ry(st, i, csc[i], css[i], t);
    __syncthreads();
  }
  for (int L = 0; L < 4; L++) {
    for (int i = 0; i < NQ; i++) {
      apply_ry(st, i, csc[10 + L * 10 + i], css[10 + L * 10 + i], t);
      __syncthreads();
    }
    for (int i = 0; i < NQ - 1; i++) {
      apply_cry(st, i, csc[50 + i], css[50 + i], t);
      __syncthreads();
    }
  }

  float z[NQ];
#pragma unroll
  for (int i = 0; i < NQ; i++) z[i] = 0.f;
#pragma unroll
  for (int r = 0; r < 4; r++) {
    int a = t + 256 * r;
    float p = st[a] * st[a];
#pragma unroll
    for (int i = 0; i < NQ; i++) z[i] += ((a >> (9 - i)) & 1) ? -p : p;
  }
#pragma unroll
  for (int off = 32; off >= 1; off >>= 1) {
#pragma unroll
    for (int i = 0; i < NQ; i++) z[i] += __shfl_down(z[i], off, 64);
  }
  int wave = t >> 6, lane = t & 63;
  if (lane == 0) {
#pragma unroll
    for (int i = 0; i < NQ; i++) zred[wave][i] = z[i];
  }
  __syncthreads();
  if (t < NQ) zq[t] = zred[0][t] + zred[1][t] + zred[2][t] + zred[3][t];
  __syncthreads();

  if (t < 16) {
    float sum = cb1[t];
    for (int k = 0; k < 128; k++) sum = fmaf(emb[k], cW1[k * 16 + t], sum);
    for (int k = 0; k < NQ; k++) sum = fmaf(zq[k], cW1[(128 + k) * 16 + t], sum);
    hid[t] = fmaxf(sum, 0.f);
  }
  __syncthreads();
  if (t == 0) {
    float sum = cb2[0];
    for (int j = 0; j < 16; j++) sum = fmaf(hid[j], cW2[j], sum);
    out[g] = sum;
  }
}

extern "C" void kernel_launch(void* const* d_in, const int* in_sizes, int n_in,
                              void* d_out, int out_size, void* d_ws, size_t ws_size,
                              hipStream_t stream) {
  const float* x = (const float*)d_in[0];
  const int* ei = (const int*)d_in[1];
  const int* batch = (const int*)d_in[2];
  const float* eattr = (const float*)d_in[3];
  const float* W1 = (const float*)d_in[4];
  const float* b1 = (const float*)d_in[5];
  const float* W2 = (const float*)d_in[6];
  const float* b2 = (const float*)d_in[7];
  const float* projW = (const float*)d_in[8];
  const float* projb = (const float*)d_in[9];
  const float* vqcW = (const float*)d_in[10];
  const float* epW = (const float*)d_in[11];
  const float* epb = (const float*)d_in[12];
  const float* cW1 = (const float*)d_in[13];
  const float* cb1 = (const float*)d_in[14];
  const float* cW2 = (const float*)d_in[15];
  const float* cb2 = (const float*)d_in[16];
  float* out = (float*)d_out;

  const int N = in_sizes[0] / 128;  // 32768
  const int E = in_sizes[1] / 2;    // 131072
  const int Bn = out_size;          // 1024

  const int* srcA = ei;
  const int* dstA = ei + E;

  char* ws = (char*)d_ws;
  float* bufA = (float*)ws;                         // 32 MB
  float* bufB = (float*)(ws + ((size_t)32 << 20));  // 32 MB
  size_t off = (size_t)64 << 20;
  auto alloc = [&](size_t bytes) {
    size_t o = off;
    off += (bytes + 255) & ~(size_t)255;
    return o;
  };
  // zeroed region: cnt, nsum4, necnt (contiguous)
  int* cnt = (int*)(ws + alloc((size_t)N * 4));
  float* nsum4 = (float*)(ws + alloc((size_t)N * 16));
  float* necnt = (float*)(ws + alloc((size_t)N * 4));
  size_t zeroEnd = off;
  int* rowStart = (int*)(ws + alloc((size_t)(N + 1) * 4));
  int* pos = (int*)(ws + alloc((size_t)N * 4));
  int* srcSorted = (int*)(ws + alloc((size_t)E * 4));
  float* dcoef = (float*)(ws + alloc((size_t)E * 4));
  float* dinv = (float*)(ws + alloc((size_t)N * 4));
  float* invdeg = (float*)(ws + alloc((size_t)N * 4));
  int* starts = (int*)(ws + alloc((size_t)(Bn + 1) * 4));
  int* incl = (int*)(ws + alloc((size_t)N * 4));
  int* bsum = (int*)(ws + alloc(64 * 4));

  hipMemsetAsync(ws + ((size_t)64 << 20), 0, zeroEnd - ((size_t)64 << 20), stream);

  int eblocks = (E + 255) / 256;
  int nblocks = (N + 255) / 256;
  int nb1024 = N >> 10;  // 32

  k_edge_setup<<<eblocks, 256, 0, stream>>>(dstA, srcA, eattr, E, cnt, nsum4, necnt);
  k_scan1<<<nb1024, 1024, 0, stream>>>(cnt, incl, bsum);
  k_node_setup<<<nblocks, 256, 0, stream>>>(cnt, incl, bsum, batch, N, Bn, rowStart, pos,
                                            dinv, invdeg, starts);
  k_fill<<<eblocks, 256, 0, stream>>>(dstA, srcA, dinv, E, pos, srcSorted, dcoef);

  {
    dim3 grid(256 / 64, N / 64);
    k_gemm<<<grid, 256, 0, stream>>>(x, W1, bufA, N, 128, 256);
  }
  k_gcn_combine<<<(N * 64) / 256, 256, 0, stream>>>(bufA, srcSorted, dcoef, rowStart,
                                                    dinv, invdeg, b1, bufB, N, 256, 6);
  {
    dim3 grid(128 / 64, N / 64);
    k_gemm<<<grid, 256, 0, stream>>>(bufB, W2, bufA, N, 256, 128);
  }
  k_gcn_combine<<<(N * 32) / 256, 256, 0, stream>>>(bufA, srcSorted, dcoef, rowStart,
                                                    dinv, invdeg, b2, bufB, N, 128, 5);
  k_vqc_head<<<Bn, 256, 0, stream>>>(bufB, starts, nsum4, necnt, projW, projb, vqcW, epW,
                                     epb, cW1, cb1, cW2, cb2, out);
}

// Round 4
// 208.763 us; speedup vs baseline: 1.4001x; 1.0020x over previous
//
#include <hip/hip_runtime.h>

#define PI_F 3.14159f
#define NQ 10

// ---------------- zero the accumulator region (replaces 41us runtime fill) ----------------
__global__ void k_zero(float4* __restrict__ p, int n4) {
  int i = blockIdx.x * blockDim.x + threadIdx.x;
  int stride = gridDim.x * blockDim.x;
  float4 z = {0.f, 0.f, 0.f, 0.f};
  for (; i < n4; i += stride) p[i] = z;
}

// ---------------- edge pass: degree count + per-src edge-attr bins ----------------
__global__ void k_edge_setup(const int* __restrict__ dstA, const int* __restrict__ srcA,
                             const float* __restrict__ eattr, int E,
                             int* __restrict__ cnt, float* __restrict__ nsum4,
                             float* __restrict__ necnt) {
  int e = blockIdx.x * blockDim.x + threadIdx.x;
  if (e >= E) return;
  atomicAdd(&cnt[dstA[e]], 1);
  int s = srcA[e];
  float4 v = *(const float4*)(eattr + (size_t)e * 4);
  atomicAdd(&nsum4[(size_t)s * 4 + 0], v.x);
  atomicAdd(&nsum4[(size_t)s * 4 + 1], v.y);
  atomicAdd(&nsum4[(size_t)s * 4 + 2], v.z);
  atomicAdd(&nsum4[(size_t)s * 4 + 3], v.w);
  atomicAdd(&necnt[s], 1.0f);
}

// ---------------- scan level 1: per-block (1024) inclusive scan ----------------
__global__ __launch_bounds__(1024) void k_scan1(const int* __restrict__ cnt,
                                                int* __restrict__ incl,
                                                int* __restrict__ bsum) {
  __shared__ int buf[1024];
  int t = threadIdx.x;
  int base = blockIdx.x << 10;
  buf[t] = cnt[base + t];
  __syncthreads();
#pragma unroll
  for (int off = 1; off < 1024; off <<= 1) {
    int x = (t >= off) ? buf[t - off] : 0;
    __syncthreads();
    buf[t] += x;
    __syncthreads();
  }
  incl[base + t] = buf[t];
  if (t == 1023) bsum[blockIdx.x] = buf[t];
}

// ---------------- node setup: rowStart, pos, deg terms, batch starts ----------------
__global__ void k_node_setup(const int* __restrict__ cnt, const int* __restrict__ incl,
                             const int* __restrict__ bsum, const int* __restrict__ batch,
                             int N, int Bn, int* __restrict__ rowStart,
                             int* __restrict__ pos, float* __restrict__ dinv,
                             float* __restrict__ invdeg, int* __restrict__ starts) {
  int i = blockIdx.x * blockDim.x + threadIdx.x;
  if (i >= N) return;
  int blk = i >> 10;  // uniform within a 256-thread block
  int pre = 0;
  for (int j = 0; j < blk; j++) pre += bsum[j];
  int c = cnt[i];
  int inc = incl[i] + pre;
  rowStart[i + 1] = inc;
  pos[i] = inc - c;
  if (i == 0) rowStart[0] = 0;
  float d = (float)c + 1.0f;
  dinv[i] = 1.0f / sqrtf(d);
  invdeg[i] = 1.0f / d;
  int b = batch[i];
  int bp = (i == 0) ? -1 : batch[i - 1];
  for (int g = bp + 1; g <= b; g++) starts[g] = i;
  if (i == N - 1) {
    for (int g = b + 1; g <= Bn; g++) starts[g] = N;
  }
}

// ---------------- fill: counting-sort edges by dst; store src + dinv[src] ----------------
__global__ void k_fill(const int* __restrict__ dst, const int* __restrict__ srcA,
                       const float* __restrict__ dinv, int E, int* __restrict__ pos,
                       int* __restrict__ srcSorted, float* __restrict__ dcoef) {
  int e = blockIdx.x * blockDim.x + threadIdx.x;
  if (e >= E) return;
  int s = srcA[e];
  int slot = atomicAdd(&pos[dst[e]], 1);
  srcSorted[slot] = s;
  dcoef[slot] = dinv[s];
}

// ---------------- fp32 tiled GEMM: C = A(MxK) * B(KxN) ----------------
__global__ __launch_bounds__(256) void k_gemm(const float* __restrict__ A,
                                              const float* __restrict__ B,
                                              float* __restrict__ C,
                                              int M, int K, int N) {
  __shared__ float As[64][36];
  __shared__ float Bs[32][68];
  int t = threadIdx.x;
  int tx = t & 15, ty = t >> 4;
  int row0 = blockIdx.y * 64, col0 = blockIdx.x * 64;
  float acc[4][4] = {};
  for (int k0 = 0; k0 < K; k0 += 32) {
#pragma unroll
    for (int rep = 0; rep < 2; rep++) {
      int slot = t + rep * 256;
      int r = slot >> 3;
      int cg = (slot & 7) << 2;
      float4 v = *(const float4*)(A + (size_t)(row0 + r) * K + (k0 + cg));
      *(float4*)&As[r][cg] = v;
      int r2 = slot >> 4;
      int cg2 = (slot & 15) << 2;
      float4 w = *(const float4*)(B + (size_t)(k0 + r2) * N + (col0 + cg2));
      *(float4*)&Bs[r2][cg2] = w;
    }
    __syncthreads();
#pragma unroll
    for (int kk = 0; kk < 32; kk++) {
      float av[4];
      av[0] = As[ty * 4 + 0][kk];
      av[1] = As[ty * 4 + 1][kk];
      av[2] = As[ty * 4 + 2][kk];
      av[3] = As[ty * 4 + 3][kk];
      float4 b4 = *(const float4*)&Bs[kk][tx << 2];
      float bv[4] = {b4.x, b4.y, b4.z, b4.w};
#pragma unroll
      for (int i = 0; i < 4; i++)
#pragma unroll
        for (int j = 0; j < 4; j++) acc[i][j] = fmaf(av[i], bv[j], acc[i][j]);
    }
    __syncthreads();
  }
#pragma unroll
  for (int i = 0; i < 4; i++) {
    float4 v = {acc[i][0], acc[i][1], acc[i][2], acc[i][3]};
    *(float4*)(C + (size_t)(row0 + ty * 4 + i) * N + (col0 + (tx << 2))) = v;
  }
}

// ---------------- GCN aggregate + self + bias + relu ----------------
__global__ __launch_bounds__(256) void k_gcn_combine(
    const float* __restrict__ hlin, const int* __restrict__ srcSorted,
    const float* __restrict__ dcoef, const int* __restrict__ rowStart,
    const float* __restrict__ dinv, const float* __restrict__ invdeg,
    const float* __restrict__ bias, float* __restrict__ hout, int N, int C, int shift) {
  int gid = blockIdx.x * blockDim.x + threadIdx.x;
  int n = gid >> shift;
  if (n >= N) return;
  int cq = (gid & ((1 << shift) - 1)) << 2;
  int e0 = rowStart[n], e1 = rowStart[n + 1];
  float di = dinv[n];
  float ax = 0.f, ay = 0.f, az = 0.f, aw = 0.f;
  for (int e = e0; e < e1; e++) {
    int s = srcSorted[e];
    float coef = dcoef[e] * di;
    float4 v = *(const float4*)(hlin + (size_t)s * C + cq);
    ax = fmaf(coef, v.x, ax);
    ay = fmaf(coef, v.y, ay);
    az = fmaf(coef, v.z, az);
    aw = fmaf(coef, v.w, aw);
  }
  float idg = invdeg[n];
  float4 hv = *(const float4*)(hlin + (size_t)n * C + cq);
  float4 bv = *(const float4*)(bias + cq);
  float4 r;
  r.x = fmaxf(fmaf(hv.x, idg, ax) + bv.x, 0.f);
  r.y = fmaxf(fmaf(hv.y, idg, ay) + bv.y, 0.f);
  r.z = fmaxf(fmaf(hv.z, idg, az) + bv.z, 0.f);
  r.w = fmaxf(fmaf(hv.w, idg, aw) + bv.w, 0.f);
  *(float4*)(hout + (size_t)n * C + cq) = r;
}

// ---------------- fused: segment-mean + edge-pool -> q_in/ep -> VQC -> head ----------------
__device__ __forceinline__ void apply_ry(float* st, int w, float c, float s, int t) {
  int str = 1 << (9 - w);
#pragma unroll
  for (int r = 0; r < 2; r++) {
    int p = t + 256 * r;
    int lo = p & (str - 1);
    int hi = p >> (9 - w);
    int a0 = (hi << (10 - w)) + lo;
    int a1 = a0 + str;
    float x0 = st[a0], x1 = st[a1];
    st[a0] = c * x0 - s * x1;
    st[a1] = s * x0 + c * x1;
  }
}

__device__ __forceinline__ void apply_cry(float* st, int w, float c, float s, int t) {
  int ts = 1 << (8 - w);
  int lo = t & (ts - 1);
  int hi = t >> (8 - w);
  int a0 = (hi << (10 - w)) + (ts << 1) + lo;
  int a1 = a0 + ts;
  float x0 = st[a0], x1 = st[a1];
  st[a0] = c * x0 - s * x1;
  st[a1] = s * x0 + c * x1;
}

__global__ __launch_bounds__(256) void k_vqc_head(
    const float* __restrict__ h2, const int* __restrict__ starts,
    const float* __restrict__ nsum4, const float* __restrict__ necnt,
    const float* __restrict__ projW, const float* __restrict__ projb,
    const float* __restrict__ vqcW, const float* __restrict__ epW,
    const float* __restrict__ epb, const float* __restrict__ cW1,
    const float* __restrict__ cb1, const float* __restrict__ cW2,
    const float* __restrict__ cb2, float* __restrict__ out) {
  int g = blockIdx.x;
  int t = threadIdx.x;
  __shared__ float st[1024];
  __shared__ float emb[128];
  __shared__ float csc[59], css[59];
  __shared__ float pool[5];
  __shared__ float zred[4][NQ];
  __shared__ float zq[NQ];
  __shared__ float hid[16];

  int s0 = starts[g], s1 = starts[g + 1];
  int cntn = s1 - s0;
  float invc = 1.0f / (float)(cntn > 0 ? cntn : 1);
  if (t < 128) {
    float sum = 0.f;
    for (int i = s0; i < s1; i++) sum += h2[(size_t)i * 128 + t];
    emb[t] = sum * invc;
  } else if (t >= 192) {
    int lane = t - 192;
    float p0 = 0.f, p1 = 0.f, p2 = 0.f, p3 = 0.f, pc = 0.f;
    for (int i = s0 + lane; i < s1; i += 64) {
      float4 v = *(const float4*)(nsum4 + (size_t)i * 4);
      p0 += v.x; p1 += v.y; p2 += v.z; p3 += v.w;
      pc += necnt[i];
    }
#pragma unroll
    for (int off = 32; off >= 1; off >>= 1) {
      p0 += __shfl_down(p0, off, 64);
      p1 += __shfl_down(p1, off, 64);
      p2 += __shfl_down(p2, off, 64);
      p3 += __shfl_down(p3, off, 64);
      pc += __shfl_down(pc, off, 64);
    }
    if (lane == 0) { pool[0] = p0; pool[1] = p1; pool[2] = p2; pool[3] = p3; pool[4] = pc; }
  }
  st[t] = 0.f; st[t + 256] = 0.f; st[t + 512] = 0.f; st[t + 768] = 0.f;
  __syncthreads();

  if (t < NQ) {
    float sum = projb[t];
    for (int k = 0; k < 128; k++) sum = fmaf(emb[k], projW[k * NQ + t], sum);
    float th = tanhf(sum) * PI_F * 0.5f;
    csc[t] = cosf(th);
    css[t] = sinf(th);
  } else if (t < NQ + 40) {
    float th = vqcW[t - NQ] * 0.5f;
    csc[t] = cosf(th);
    css[t] = sinf(th);
  } else if (t < 59) {
    int i = t - 50;
    float icnt = 1.0f / fmaxf(pool[4], 1.0f);
    float sum = epb[i];
    for (int j = 0; j < 4; j++) sum = fmaf(pool[j] * icnt, epW[j * 9 + i], sum);
    float th = sum * 0.5f;
    csc[t] = cosf(th);
    css[t] = sinf(th);
  }
  if (t == 0) st[0] = 1.0f;
  __syncthreads();

  for (int i = 0; i < NQ; i++) {
    apply_ry(st, i, csc[i], css[i], t);
    __syncthreads();
  }
  for (int L = 0; L < 4; L++) {
    for (int i = 0; i < NQ; i++) {
      apply_ry(st, i, csc[10 + L * 10 + i], css[10 + L * 10 + i], t);
      __syncthreads();
    }
    for (int i = 0; i < NQ - 1; i++) {
      apply_cry(st, i, csc[50 + i], css[50 + i], t);
      __syncthreads();
    }
  }

  float z[NQ];
#pragma unroll
  for (int i = 0; i < NQ; i++) z[i] = 0.f;
#pragma unroll
  for (int r = 0; r < 4; r++) {
    int a = t + 256 * r;
    float p = st[a] * st[a];
#pragma unroll
    for (int i = 0; i < NQ; i++) z[i] += ((a >> (9 - i)) & 1) ? -p : p;
  }
#pragma unroll
  for (int off = 32; off >= 1; off >>= 1) {
#pragma unroll
    for (int i = 0; i < NQ; i++) z[i] += __shfl_down(z[i], off, 64);
  }
  int wave = t >> 6, lane = t & 63;
  if (lane == 0) {
#pragma unroll
    for (int i = 0; i < NQ; i++) zred[wave][i] = z[i];
  }
  __syncthreads();
  if (t < NQ) zq[t] = zred[0][t] + zred[1][t] + zred[2][t] + zred[3][t];
  __syncthreads();

  if (t < 16) {
    float sum = cb1[t];
    for (int k = 0; k < 128; k++) sum = fmaf(emb[k], cW1[k * 16 + t], sum);
    for (int k = 0; k < NQ; k++) sum = fmaf(zq[k], cW1[(128 + k) * 16 + t], sum);
    hid[t] = fmaxf(sum, 0.f);
  }
  __syncthreads();
  if (t == 0) {
    float sum = cb2[0];
    for (int j = 0; j < 16; j++) sum = fmaf(hid[j], cW2[j], sum);
    out[g] = sum;
  }
}

extern "C" void kernel_launch(void* const* d_in, const int* in_sizes, int n_in,
                              void* d_out, int out_size, void* d_ws, size_t ws_size,
                              hipStream_t stream) {
  const float* x = (const float*)d_in[0];
  const int* ei = (const int*)d_in[1];
  const int* batch = (const int*)d_in[2];
  const float* eattr = (const float*)d_in[3];
  const float* W1 = (const float*)d_in[4];
  const float* b1 = (const float*)d_in[5];
  const float* W2 = (const float*)d_in[6];
  const float* b2 = (const float*)d_in[7];
  const float* projW = (const float*)d_in[8];
  const float* projb = (const float*)d_in[9];
  const float* vqcW = (const float*)d_in[10];
  const float* epW = (const float*)d_in[11];
  const float* epb = (const float*)d_in[12];
  const float* cW1 = (const float*)d_in[13];
  const float* cb1 = (const float*)d_in[14];
  const float* cW2 = (const float*)d_in[15];
  const float* cb2 = (const float*)d_in[16];
  float* out = (float*)d_out;

  const int N = in_sizes[0] / 128;  // 32768
  const int E = in_sizes[1] / 2;    // 131072
  const int Bn = out_size;          // 1024

  const int* srcA = ei;
  const int* dstA = ei + E;

  char* ws = (char*)d_ws;
  float* bufA = (float*)ws;                         // 32 MB
  float* bufB = (float*)(ws + ((size_t)32 << 20));  // 32 MB
  size_t off = (size_t)64 << 20;
  auto alloc = [&](size_t bytes) {
    size_t o = off;
    off += (bytes + 255) & ~(size_t)255;
    return o;
  };
  // zeroed region: cnt, nsum4, necnt (contiguous)
  int* cnt = (int*)(ws + alloc((size_t)N * 4));
  float* nsum4 = (float*)(ws + alloc((size_t)N * 16));
  float* necnt = (float*)(ws + alloc((size_t)N * 4));
  size_t zeroEnd = off;
  int* rowStart = (int*)(ws + alloc((size_t)(N + 1) * 4));
  int* pos = (int*)(ws + alloc((size_t)N * 4));
  int* srcSorted = (int*)(ws + alloc((size_t)E * 4));
  float* dcoef = (float*)(ws + alloc((size_t)E * 4));
  float* dinv = (float*)(ws + alloc((size_t)N * 4));
  float* invdeg = (float*)(ws + alloc((size_t)N * 4));
  int* starts = (int*)(ws + alloc((size_t)(Bn + 1) * 4));
  int* incl = (int*)(ws + alloc((size_t)N * 4));
  int* bsum = (int*)(ws + alloc(64 * 4));

  int eblocks = (E + 255) / 256;
  int nblocks = (N + 255) / 256;
  int nb1024 = N >> 10;  // 32

  // zero accumulators with our own kernel (runtime fill path costs 41us)
  int zero4 = (int)((zeroEnd - ((size_t)64 << 20)) / 16);
  k_zero<<<(zero4 + 255) / 256, 256, 0, stream>>>((float4*)(ws + ((size_t)64 << 20)), zero4);

  k_edge_setup<<<eblocks, 256, 0, stream>>>(dstA, srcA, eattr, E, cnt, nsum4, necnt);
  k_scan1<<<nb1024, 1024, 0, stream>>>(cnt, incl, bsum);
  k_node_setup<<<nblocks, 256, 0, stream>>>(cnt, incl, bsum, batch, N, Bn, rowStart, pos,
                                            dinv, invdeg, starts);
  k_fill<<<eblocks, 256, 0, stream>>>(dstA, srcA, dinv, E, pos, srcSorted, dcoef);

  {
    dim3 grid(256 / 64, N / 64);
    k_gemm<<<grid, 256, 0, stream>>>(x, W1, bufA, N, 128, 256);
  }
  k_gcn_combine<<<(N * 64) / 256, 256, 0, stream>>>(bufA, srcSorted, dcoef, rowStart,
                                                    dinv, invdeg, b1, bufB, N, 256, 6);
  {
    dim3 grid(128 / 64, N / 64);
    k_gemm<<<grid, 256, 0, stream>>>(bufB, W2, bufA, N, 256, 128);
  }
  k_gcn_combine<<<(N * 32) / 256, 256, 0, stream>>>(bufA, srcSorted, dcoef, rowStart,
                                                    dinv, invdeg, b2, bufB, N, 128, 5);
  k_vqc_head<<<Bn, 256, 0, stream>>>(bufB, starts, nsum4, necnt, projW, projb, vqcW, epW,
                                     epb, cW1, cb1, cW2, cb2, out);
}

// Round 5
// 193.360 us; speedup vs baseline: 1.5116x; 1.0797x over previous
//
#include <hip/hip_runtime.h>

#define PI_F 3.14159f
#define NQ 10
#define PB 64  // partial blocks for edge pooling

// ---------------- zero the accumulator region ----------------
__global__ void k_zero(float4* __restrict__ p, int n4) {
  int i = blockIdx.x * blockDim.x + threadIdx.x;
  int stride = gridDim.x * blockDim.x;
  float4 z = {0.f, 0.f, 0.f, 0.f};
  for (; i < n4; i += stride) p[i] = z;
}

// ---------------- dst-degree histogram (1 atomic/edge) ----------------
__global__ void k_count(const int* __restrict__ dstA, int E, int* __restrict__ cnt) {
  int e = blockIdx.x * blockDim.x + threadIdx.x;
  if (e < E) atomicAdd(&cnt[dstA[e]], 1);
}

// ---------------- edge-attr pooling: LDS bins + block partials (no global atomics) ----------------
__global__ __launch_bounds__(1024) void k_edge_pool(const int* __restrict__ srcA,
                                                    const int* __restrict__ batch,
                                                    const float* __restrict__ eattr, int E,
                                                    float* __restrict__ part) {
  __shared__ float bins[1024 * 5];
  int t = threadIdx.x;
  for (int i = t; i < 5120; i += 1024) bins[i] = 0.f;
  __syncthreads();
  int per = (E + gridDim.x - 1) / gridDim.x;
  int base = blockIdx.x * per;
  int end = min(base + per, E);
  for (int e = base + t; e < end; e += 1024) {
    int s = srcA[e];
    int g = batch[s];
    float4 v = *(const float4*)(eattr + (size_t)e * 4);
    atomicAdd(&bins[g * 5 + 0], v.x);
    atomicAdd(&bins[g * 5 + 1], v.y);
    atomicAdd(&bins[g * 5 + 2], v.z);
    atomicAdd(&bins[g * 5 + 3], v.w);
    atomicAdd(&bins[g * 5 + 4], 1.0f);
  }
  __syncthreads();
  float* dst = part + (size_t)blockIdx.x * 5120;
  for (int i = t; i < 5120; i += 1024) dst[i] = bins[i];
}

// ---------------- scan level 1: per-block (1024) inclusive scan ----------------
__global__ __launch_bounds__(1024) void k_scan1(const int* __restrict__ cnt,
                                                int* __restrict__ incl,
                                                int* __restrict__ bsum) {
  __shared__ int buf[1024];
  int t = threadIdx.x;
  int base = blockIdx.x << 10;
  buf[t] = cnt[base + t];
  __syncthreads();
#pragma unroll
  for (int off = 1; off < 1024; off <<= 1) {
    int x = (t >= off) ? buf[t - off] : 0;
    __syncthreads();
    buf[t] += x;
    __syncthreads();
  }
  incl[base + t] = buf[t];
  if (t == 1023) bsum[blockIdx.x] = buf[t];
}

// ---------------- node setup: rowStart, pos, deg terms, batch starts ----------------
__global__ void k_node_setup(const int* __restrict__ cnt, const int* __restrict__ incl,
                             const int* __restrict__ bsum, const int* __restrict__ batch,
                             int N, int Bn, int* __restrict__ rowStart,
                             int* __restrict__ pos, float* __restrict__ dinv,
                             float* __restrict__ invdeg, int* __restrict__ starts) {
  int i = blockIdx.x * blockDim.x + threadIdx.x;
  if (i >= N) return;
  int blk = i >> 10;
  int pre = 0;
  for (int j = 0; j < blk; j++) pre += bsum[j];
  int c = cnt[i];
  int inc = incl[i] + pre;
  rowStart[i + 1] = inc;
  pos[i] = inc - c;
  if (i == 0) rowStart[0] = 0;
  float d = (float)c + 1.0f;
  dinv[i] = 1.0f / sqrtf(d);
  invdeg[i] = 1.0f / d;
  int b = batch[i];
  int bp = (i == 0) ? -1 : batch[i - 1];
  for (int g = bp + 1; g <= b; g++) starts[g] = i;
  if (i == N - 1) {
    for (int g = b + 1; g <= Bn; g++) starts[g] = N;
  }
}

// ---------------- fill: counting-sort edges by dst; store src + dinv[src] ----------------
__global__ void k_fill(const int* __restrict__ dst, const int* __restrict__ srcA,
                       const float* __restrict__ dinv, int E, int* __restrict__ pos,
                       int* __restrict__ srcSorted, float* __restrict__ dcoef) {
  int e = blockIdx.x * blockDim.x + threadIdx.x;
  if (e >= E) return;
  int s = srcA[e];
  int slot = atomicAdd(&pos[dst[e]], 1);
  srcSorted[slot] = s;
  dcoef[slot] = dinv[s];
}

// ---------------- fp32 tiled GEMM: C = A(MxK) * B(KxN) ----------------
__global__ __launch_bounds__(256) void k_gemm(const float* __restrict__ A,
                                              const float* __restrict__ B,
                                              float* __restrict__ C,
                                              int M, int K, int N) {
  __shared__ float As[64][36];
  __shared__ float Bs[32][68];
  int t = threadIdx.x;
  int tx = t & 15, ty = t >> 4;
  int row0 = blockIdx.y * 64, col0 = blockIdx.x * 64;
  float acc[4][4] = {};
  for (int k0 = 0; k0 < K; k0 += 32) {
#pragma unroll
    for (int rep = 0; rep < 2; rep++) {
      int slot = t + rep * 256;
      int r = slot >> 3;
      int cg = (slot & 7) << 2;
      float4 v = *(const float4*)(A + (size_t)(row0 + r) * K + (k0 + cg));
      *(float4*)&As[r][cg] = v;
      int r2 = slot >> 4;
      int cg2 = (slot & 15) << 2;
      float4 w = *(const float4*)(B + (size_t)(k0 + r2) * N + (col0 + cg2));
      *(float4*)&Bs[r2][cg2] = w;
    }
    __syncthreads();
#pragma unroll
    for (int kk = 0; kk < 32; kk++) {
      float av[4];
      av[0] = As[ty * 4 + 0][kk];
      av[1] = As[ty * 4 + 1][kk];
      av[2] = As[ty * 4 + 2][kk];
      av[3] = As[ty * 4 + 3][kk];
      float4 b4 = *(const float4*)&Bs[kk][tx << 2];
      float bv[4] = {b4.x, b4.y, b4.z, b4.w};
#pragma unroll
      for (int i = 0; i < 4; i++)
#pragma unroll
        for (int j = 0; j < 4; j++) acc[i][j] = fmaf(av[i], bv[j], acc[i][j]);
    }
    __syncthreads();
  }
#pragma unroll
  for (int i = 0; i < 4; i++) {
    float4 v = {acc[i][0], acc[i][1], acc[i][2], acc[i][3]};
    *(float4*)(C + (size_t)(row0 + ty * 4 + i) * N + (col0 + (tx << 2))) = v;
  }
}

// ---------------- GCN aggregate + self + bias + relu ----------------
__global__ __launch_bounds__(256) void k_gcn_combine(
    const float* __restrict__ hlin, const int* __restrict__ srcSorted,
    const float* __restrict__ dcoef, const int* __restrict__ rowStart,
    const float* __restrict__ dinv, const float* __restrict__ invdeg,
    const float* __restrict__ bias, float* __restrict__ hout, int N, int C, int shift) {
  int gid = blockIdx.x * blockDim.x + threadIdx.x;
  int n = gid >> shift;
  if (n >= N) return;
  int cq = (gid & ((1 << shift) - 1)) << 2;
  int e0 = rowStart[n], e1 = rowStart[n + 1];
  float di = dinv[n];
  float ax = 0.f, ay = 0.f, az = 0.f, aw = 0.f;
  for (int e = e0; e < e1; e++) {
    int s = srcSorted[e];
    float coef = dcoef[e] * di;
    float4 v = *(const float4*)(hlin + (size_t)s * C + cq);
    ax = fmaf(coef, v.x, ax);
    ay = fmaf(coef, v.y, ay);
    az = fmaf(coef, v.z, az);
    aw = fmaf(coef, v.w, aw);
  }
  float idg = invdeg[n];
  float4 hv = *(const float4*)(hlin + (size_t)n * C + cq);
  float4 bv = *(const float4*)(bias + cq);
  float4 r;
  r.x = fmaxf(fmaf(hv.x, idg, ax) + bv.x, 0.f);
  r.y = fmaxf(fmaf(hv.y, idg, ay) + bv.y, 0.f);
  r.z = fmaxf(fmaf(hv.z, idg, az) + bv.z, 0.f);
  r.w = fmaxf(fmaf(hv.w, idg, aw) + bv.w, 0.f);
  *(float4*)(hout + (size_t)n * C + cq) = r;
}

// ---------------- fused: segment-mean + edge-pool reduce -> q_in/ep -> VQC -> head ----------------
__device__ __forceinline__ void apply_ry(float* st, int w, float c, float s, int t) {
  int str = 1 << (9 - w);
#pragma unroll
  for (int r = 0; r < 2; r++) {
    int p = t + 256 * r;
    int lo = p & (str - 1);
    int hi = p >> (9 - w);
    int a0 = (hi << (10 - w)) + lo;
    int a1 = a0 + str;
    float x0 = st[a0], x1 = st[a1];
    st[a0] = c * x0 - s * x1;
    st[a1] = s * x0 + c * x1;
  }
}

__device__ __forceinline__ void apply_cry(float* st, int w, float c, float s, int t) {
  int ts = 1 << (8 - w);
  int lo = t & (ts - 1);
  int hi = t >> (8 - w);
  int a0 = (hi << (10 - w)) + (ts << 1) + lo;
  int a1 = a0 + ts;
  float x0 = st[a0], x1 = st[a1];
  st[a0] = c * x0 - s * x1;
  st[a1] = s * x0 + c * x1;
}

__global__ __launch_bounds__(256) void k_vqc_head(
    const float* __restrict__ h2, const int* __restrict__ starts,
    const float* __restrict__ part, const float* __restrict__ projW,
    const float* __restrict__ projb, const float* __restrict__ vqcW,
    const float* __restrict__ epW, const float* __restrict__ epb,
    const float* __restrict__ cW1, const float* __restrict__ cb1,
    const float* __restrict__ cW2, const float* __restrict__ cb2,
    float* __restrict__ out) {
  int g = blockIdx.x;
  int t = threadIdx.x;
  __shared__ float st[1024];
  __shared__ float emb[128];
  __shared__ float csc[59], css[59];
  __shared__ float pool[5];
  __shared__ float zred[4][NQ];
  __shared__ float zq[NQ];
  __shared__ float hid[16];

  int s0 = starts[g], s1 = starts[g + 1];
  int cntn = s1 - s0;
  float invc = 1.0f / (float)(cntn > 0 ? cntn : 1);
  if (t < 128) {
    float sum = 0.f;
    for (int i = s0; i < s1; i++) sum += h2[(size_t)i * 128 + t];
    emb[t] = sum * invc;
  } else if (t >= 192) {
    // wave 3: reduce PB block partials for this graph
    int lane = t - 192;
    float p0 = 0.f, p1 = 0.f, p2 = 0.f, p3 = 0.f, pc = 0.f;
    for (int b = lane; b < PB; b += 64) {
      const float* pp = part + (size_t)b * 5120 + g * 5;
      p0 += pp[0]; p1 += pp[1]; p2 += pp[2]; p3 += pp[3]; pc += pp[4];
    }
#pragma unroll
    for (int off = 32; off >= 1; off >>= 1) {
      p0 += __shfl_down(p0, off, 64);
      p1 += __shfl_down(p1, off, 64);
      p2 += __shfl_down(p2, off, 64);
      p3 += __shfl_down(p3, off, 64);
      pc += __shfl_down(pc, off, 64);
    }
    if (lane == 0) { pool[0] = p0; pool[1] = p1; pool[2] = p2; pool[3] = p3; pool[4] = pc; }
  }
  st[t] = 0.f; st[t + 256] = 0.f; st[t + 512] = 0.f; st[t + 768] = 0.f;
  __syncthreads();

  if (t < NQ) {
    float sum = projb[t];
    for (int k = 0; k < 128; k++) sum = fmaf(emb[k], projW[k * NQ + t], sum);
    float th = tanhf(sum) * PI_F * 0.5f;
    csc[t] = cosf(th);
    css[t] = sinf(th);
  } else if (t < NQ + 40) {
    float th = vqcW[t - NQ] * 0.5f;
    csc[t] = cosf(th);
    css[t] = sinf(th);
  } else if (t < 59) {
    int i = t - 50;
    float icnt = 1.0f / fmaxf(pool[4], 1.0f);
    float sum = epb[i];
    for (int j = 0; j < 4; j++) sum = fmaf(pool[j] * icnt, epW[j * 9 + i], sum);
    float th = sum * 0.5f;
    csc[t] = cosf(th);
    css[t] = sinf(th);
  }
  if (t == 0) st[0] = 1.0f;
  __syncthreads();

  for (int i = 0; i < NQ; i++) {
    apply_ry(st, i, csc[i], css[i], t);
    __syncthreads();
  }
  for (int L = 0; L < 4; L++) {
    for (int i = 0; i < NQ; i++) {
      apply_ry(st, i, csc[10 + L * 10 + i], css[10 + L * 10 + i], t);
      __syncthreads();
    }
    for (int i = 0; i < NQ - 1; i++) {
      apply_cry(st, i, csc[50 + i], css[50 + i], t);
      __syncthreads();
    }
  }

  float z[NQ];
#pragma unroll
  for (int i = 0; i < NQ; i++) z[i] = 0.f;
#pragma unroll
  for (int r = 0; r < 4; r++) {
    int a = t + 256 * r;
    float p = st[a] * st[a];
#pragma unroll
    for (int i = 0; i < NQ; i++) z[i] += ((a >> (9 - i)) & 1) ? -p : p;
  }
#pragma unroll
  for (int off = 32; off >= 1; off >>= 1) {
#pragma unroll
    for (int i = 0; i < NQ; i++) z[i] += __shfl_down(z[i], off, 64);
  }
  int wave = t >> 6, lane = t & 63;
  if (lane == 0) {
#pragma unroll
    for (int i = 0; i < NQ; i++) zred[wave][i] = z[i];
  }
  __syncthreads();
  if (t < NQ) zq[t] = zred[0][t] + zred[1][t] + zred[2][t] + zred[3][t];
  __syncthreads();

  if (t < 16) {
    float sum = cb1[t];
    for (int k = 0; k < 128; k++) sum = fmaf(emb[k], cW1[k * 16 + t], sum);
    for (int k = 0; k < NQ; k++) sum = fmaf(zq[k], cW1[(128 + k) * 16 + t], sum);
    hid[t] = fmaxf(sum, 0.f);
  }
  __syncthreads();
  if (t == 0) {
    float sum = cb2[0];
    for (int j = 0; j < 16; j++) sum = fmaf(hid[j], cW2[j], sum);
    out[g] = sum;
  }
}

extern "C" void kernel_launch(void* const* d_in, const int* in_sizes, int n_in,
                              void* d_out, int out_size, void* d_ws, size_t ws_size,
                              hipStream_t stream) {
  const float* x = (const float*)d_in[0];
  const int* ei = (const int*)d_in[1];
  const int* batch = (const int*)d_in[2];
  const float* eattr = (const float*)d_in[3];
  const float* W1 = (const float*)d_in[4];
  const float* b1 = (const float*)d_in[5];
  const float* W2 = (const float*)d_in[6];
  const float* b2 = (const float*)d_in[7];
  const float* projW = (const float*)d_in[8];
  const float* projb = (const float*)d_in[9];
  const float* vqcW = (const float*)d_in[10];
  const float* epW = (const float*)d_in[11];
  const float* epb = (const float*)d_in[12];
  const float* cW1 = (const float*)d_in[13];
  const float* cb1 = (const float*)d_in[14];
  const float* cW2 = (const float*)d_in[15];
  const float* cb2 = (const float*)d_in[16];
  float* out = (float*)d_out;

  const int N = in_sizes[0] / 128;  // 32768
  const int E = in_sizes[1] / 2;    // 131072
  const int Bn = out_size;          // 1024

  const int* srcA = ei;
  const int* dstA = ei + E;

  char* ws = (char*)d_ws;
  float* bufA = (float*)ws;                         // 32 MB
  float* bufB = (float*)(ws + ((size_t)32 << 20));  // 32 MB
  size_t off = (size_t)64 << 20;
  auto alloc = [&](size_t bytes) {
    size_t o = off;
    off += (bytes + 255) & ~(size_t)255;
    return o;
  };
  // zeroed region: cnt only
  int* cnt = (int*)(ws + alloc((size_t)N * 4));
  size_t zeroEnd = off;
  float* part = (float*)(ws + alloc((size_t)PB * 5120 * 4));
  int* rowStart = (int*)(ws + alloc((size_t)(N + 1) * 4));
  int* pos = (int*)(ws + alloc((size_t)N * 4));
  int* srcSorted = (int*)(ws + alloc((size_t)E * 4));
  float* dcoef = (float*)(ws + alloc((size_t)E * 4));
  float* dinv = (float*)(ws + alloc((size_t)N * 4));
  float* invdeg = (float*)(ws + alloc((size_t)N * 4));
  int* starts = (int*)(ws + alloc((size_t)(Bn + 1) * 4));
  int* incl = (int*)(ws + alloc((size_t)N * 4));
  int* bsum = (int*)(ws + alloc(64 * 4));

  int eblocks = (E + 255) / 256;
  int nblocks = (N + 255) / 256;
  int nb1024 = N >> 10;  // 32

  int zero4 = (int)((zeroEnd - ((size_t)64 << 20)) / 16);
  k_zero<<<(zero4 + 255) / 256, 256, 0, stream>>>((float4*)(ws + ((size_t)64 << 20)), zero4);

  k_count<<<eblocks, 256, 0, stream>>>(dstA, E, cnt);
  k_edge_pool<<<PB, 1024, 0, stream>>>(srcA, batch, eattr, E, part);
  k_scan1<<<nb1024, 1024, 0, stream>>>(cnt, incl, bsum);
  k_node_setup<<<nblocks, 256, 0, stream>>>(cnt, incl, bsum, batch, N, Bn, rowStart, pos,
                                            dinv, invdeg, starts);
  k_fill<<<eblocks, 256, 0, stream>>>(dstA, srcA, dinv, E, pos, srcSorted, dcoef);

  {
    dim3 grid(256 / 64, N / 64);
    k_gemm<<<grid, 256, 0, stream>>>(x, W1, bufA, N, 128, 256);
  }
  k_gcn_combine<<<(N * 64) / 256, 256, 0, stream>>>(bufA, srcSorted, dcoef, rowStart,
                                                    dinv, invdeg, b1, bufB, N, 256, 6);
  {
    dim3 grid(128 / 64, N / 64);
    k_gemm<<<grid, 256, 0, stream>>>(bufB, W2, bufA, N, 256, 128);
  }
  k_gcn_combine<<<(N * 32) / 256, 256, 0, stream>>>(bufA, srcSorted, dcoef, rowStart,
                                                    dinv, invdeg, b2, bufB, N, 128, 5);
  k_vqc_head<<<Bn, 256, 0, stream>>>(bufB, starts, part, projW, projb, vqcW, epW,
                                     epb, cW1, cb1, cW2, cb2, out);
}